// Round 1
// baseline (5321.046 us; speedup 1.0000x reference)
//
#include <hip/hip_runtime.h>
#include <stdint.h>

#define NB 128
#define NT 2048
#define NI 128
#define NH 1024
#define NO 128

// ---------------------------------------------------------------------------
// Phase A: fused GEMM1 + LIF layer 1.
// grid = 512 (128 b * 4 htiles), block = 256. Each thread owns one h neuron:
// W1 row in VGPRs, x row is wave-uniform (expect s_load), sequential t scan.
// Emits spikes either as u8 [t][b][h] or packed bits [t][b][h/64].
// ---------------------------------------------------------------------------
template <int STORE_BITS>
__global__ __launch_bounds__(256, 2) void snn_phaseA(
    const float* __restrict__ x, const float* __restrict__ W1,
    const float* __restrict__ b1, uint8_t* __restrict__ s1u8,
    uint64_t* __restrict__ s1bits)
{
    const int b = blockIdx.x >> 2;
    const int htile = blockIdx.x & 3;
    const int tid = threadIdx.x;
    const int h = htile * 256 + tid;

    float wk[NI];
#pragma unroll
    for (int k = 0; k < NI; ++k) wk[k] = W1[(size_t)h * NI + k];
    const float bias = b1[h];

    const float* __restrict__ xb = x + (size_t)b * NT * NI;
    float v = 0.0f;

    for (int t = 0; t < NT; ++t) {
        const float* __restrict__ xr = xb + (size_t)t * NI;
        float a0 = 0.f, a1 = 0.f, a2 = 0.f, a3 = 0.f;
#pragma unroll
        for (int k = 0; k < NI; k += 4) {
            a0 = fmaf(xr[k + 0], wk[k + 0], a0);
            a1 = fmaf(xr[k + 1], wk[k + 1], a1);
            a2 = fmaf(xr[k + 2], wk[k + 2], a2);
            a3 = fmaf(xr[k + 3], wk[k + 3], a3);
        }
        const float h1 = ((a0 + a1) + (a2 + a3)) + bias;
        // LIF: decay_input=True, tau=2, v_th=1, hard reset to 0.
        v = v + (h1 - v) * 0.5f;
        const bool sp = (v >= 1.0f);
        v = sp ? 0.0f : v;

        if (STORE_BITS) {
            const unsigned long long m = __ballot(sp);
            if ((tid & 63) == 0) {
                const int wv = tid >> 6;  // wave id 0..3; covers h = htile*256+wv*64+lane
                s1bits[((size_t)t * NB + b) * (NH / 64) + htile * 4 + wv] =
                    (uint64_t)m;
            }
        } else {
            s1u8[((size_t)t * NB + b) * NH + h] = sp ? (uint8_t)1 : (uint8_t)0;
        }
    }
}

// ---------------------------------------------------------------------------
// Phase C: fused GEMM2 + LIF layer 2 + decision-window sum.
// grid = 512 (128 b * 4 otiles of 32 o), block = 256.
// thread = (hs = tid>>5 in 0..7, o = otile*32 + (tid&31)); W2 slice (128
// floats) in VGPRs. Per t: partial dot over 128 h, shfl+LDS reduce over hs,
// wave0 lanes 0..31 run the v2 LIF and accumulate spike counts for t>=T/2.
// ---------------------------------------------------------------------------
template <int LOAD_BITS>
__global__ __launch_bounds__(256, 2) void snn_phaseC(
    const uint8_t* __restrict__ s1u8, const uint64_t* __restrict__ s1bits,
    const float* __restrict__ W2, const float* __restrict__ b2,
    float* __restrict__ out)
{
    const int b = blockIdx.x >> 2;
    const int otile = blockIdx.x & 3;
    const int tid = threadIdx.x;
    const int o = otile * 32 + (tid & 31);
    const int hs = tid >> 5;  // 0..7, covers h = hs*128 .. hs*128+127

    float wk[128];
#pragma unroll
    for (int k = 0; k < 128; ++k)
        wk[k] = W2[(size_t)o * NH + hs * 128 + k];

    __shared__ float red[2][4][32];

    float v = 0.0f, cnt = 0.0f;
    const float bias = b2[o];
    const int wv = tid >> 6;

    for (int t = 0; t < NT; ++t) {
        float a0 = 0.f, a1 = 0.f, a2 = 0.f, a3 = 0.f;
        if (LOAD_BITS) {
            const uint64_t* sr =
                s1bits + ((size_t)t * NB + b) * (NH / 64) + hs * 2;
            const uint64_t wd0 = sr[0];
            const uint64_t wd1 = sr[1];
            const uint32_t q0 = (uint32_t)wd0, q1 = (uint32_t)(wd0 >> 32);
            const uint32_t q2 = (uint32_t)wd1, q3 = (uint32_t)(wd1 >> 32);
#pragma unroll
            for (int k = 0; k < 32; ++k) {
                const int sh = 31 - k;
                a0 += __int_as_float(((int)(q0 << sh) >> 31) &
                                     __float_as_int(wk[k]));
                a1 += __int_as_float(((int)(q1 << sh) >> 31) &
                                     __float_as_int(wk[32 + k]));
                a2 += __int_as_float(((int)(q2 << sh) >> 31) &
                                     __float_as_int(wk[64 + k]));
                a3 += __int_as_float(((int)(q3 << sh) >> 31) &
                                     __float_as_int(wk[96 + k]));
            }
        } else {
            const uint8_t* sr = s1u8 + ((size_t)t * NB + b) * NH + hs * 128;
#pragma unroll
            for (int j = 0; j < 8; ++j) {
                const uint4 u = *reinterpret_cast<const uint4*>(sr + j * 16);
                const int kb = j * 16;
                // byte -> float should lower to v_cvt_f32_ubyte{0..3}
                a0 = fmaf((float)((u.x >> 0) & 0xffu), wk[kb + 0], a0);
                a1 = fmaf((float)((u.x >> 8) & 0xffu), wk[kb + 1], a1);
                a2 = fmaf((float)((u.x >> 16) & 0xffu), wk[kb + 2], a2);
                a3 = fmaf((float)((u.x >> 24) & 0xffu), wk[kb + 3], a3);
                a0 = fmaf((float)((u.y >> 0) & 0xffu), wk[kb + 4], a0);
                a1 = fmaf((float)((u.y >> 8) & 0xffu), wk[kb + 5], a1);
                a2 = fmaf((float)((u.y >> 16) & 0xffu), wk[kb + 6], a2);
                a3 = fmaf((float)((u.y >> 24) & 0xffu), wk[kb + 7], a3);
                a0 = fmaf((float)((u.z >> 0) & 0xffu), wk[kb + 8], a0);
                a1 = fmaf((float)((u.z >> 8) & 0xffu), wk[kb + 9], a1);
                a2 = fmaf((float)((u.z >> 16) & 0xffu), wk[kb + 10], a2);
                a3 = fmaf((float)((u.z >> 24) & 0xffu), wk[kb + 11], a3);
                a0 = fmaf((float)((u.w >> 0) & 0xffu), wk[kb + 12], a0);
                a1 = fmaf((float)((u.w >> 8) & 0xffu), wk[kb + 13], a1);
                a2 = fmaf((float)((u.w >> 16) & 0xffu), wk[kb + 14], a2);
                a3 = fmaf((float)((u.w >> 24) & 0xffu), wk[kb + 15], a3);
            }
        }
        float partial = (a0 + a1) + (a2 + a3);
        // pair-reduce hs within wave: lane l <-> l^32 swaps hs parity
        partial += __shfl_xor(partial, 32, 64);
        if ((tid & 63) < 32) red[t & 1][wv][tid & 31] = partial;
        __syncthreads();
        if (tid < 32) {
            const float h2 =
                ((red[t & 1][0][tid] + red[t & 1][1][tid]) +
                 (red[t & 1][2][tid] + red[t & 1][3][tid])) + bias;
            v = v + (h2 - v) * 0.5f;
            const bool sp = (v >= 1.0f);
            v = sp ? 0.0f : v;
            if (t >= NT / 2) cnt += sp ? 1.0f : 0.0f;
        }
        // next t writes the other LDS slot; wave0's read above is ordered
        // before any re-write of this slot by the following barrier.
    }
    if (tid < 32) out[(size_t)b * NO + otile * 32 + tid] = cnt;
}

extern "C" void kernel_launch(void* const* d_in, const int* in_sizes, int n_in,
                              void* d_out, int out_size, void* d_ws,
                              size_t ws_size, hipStream_t stream)
{
    const float* x  = (const float*)d_in[0];
    const float* W1 = (const float*)d_in[1];
    const float* b1 = (const float*)d_in[2];
    const float* W2 = (const float*)d_in[3];
    const float* b2 = (const float*)d_in[4];
    float* out = (float*)d_out;

    const size_t need_u8 = (size_t)NT * NB * NH;  // 268 MB spike bytes

    if (ws_size >= need_u8) {
        uint8_t* s1 = (uint8_t*)d_ws;
        snn_phaseA<0><<<dim3(512), dim3(256), 0, stream>>>(x, W1, b1, s1, nullptr);
        snn_phaseC<0><<<dim3(512), dim3(256), 0, stream>>>(s1, nullptr, W2, b2, out);
    } else {
        uint64_t* s1 = (uint64_t*)d_ws;  // 33.5 MB packed bits
        snn_phaseA<1><<<dim3(512), dim3(256), 0, stream>>>(x, W1, b1, nullptr, s1);
        snn_phaseC<1><<<dim3(512), dim3(256), 0, stream>>>(nullptr, s1, W2, b2, out);
    }
}

// Round 2
// 2493.200 us; speedup vs baseline: 2.1342x; 2.1342x over previous
//
#include <hip/hip_runtime.h>
#include <stdint.h>

#define NB 128
#define NT 2048
#define NI 128
#define NH 1024
#define NO 128

// ---------------------------------------------------------------------------
// W2T: transpose W2 [O][H] -> W2T [H][O] so phase B's per-k weight row is
// contiguous (128 B) and wave-uniform -> s_load into SGPRs.
// ---------------------------------------------------------------------------
__global__ __launch_bounds__(256) void w2t_kernel(
    const float* __restrict__ W2, float* __restrict__ W2T)
{
    const int idx = blockIdx.x * 256 + threadIdx.x;  // 0..131071
    const int o = idx >> 10;                         // 0..127
    const int k = idx & 1023;                        // 0..1023
    W2T[(size_t)k * NO + o] = W2[idx];               // coalesced read
}

// ---------------------------------------------------------------------------
// Phase A: fused GEMM1 + LIF1, bit-packed spike output.
// grid = 1024 (128 b x 8 htiles of 128 h), block = 256 = 4 waves:
//   wv 0,1: k-half 0, h-group 0/1 (these waves own LIF state + stores)
//   wv 2,3: k-half 1, h-group 0/1 (supply partial sums via LDS)
// wk[64] per lane (fits VGPR for real this time); x chunk is wave-uniform
// (readfirstlane'd offset) -> expect s_load + v_fmac(sgpr) at ~64 fma/t/wave.
// One barrier per t; LDS double-buffered by t&1.
// ---------------------------------------------------------------------------
__global__ __launch_bounds__(256, 4) void snn_phaseA(
    const float* __restrict__ x, const float* __restrict__ W1,
    const float* __restrict__ b1, uint64_t* __restrict__ s1bits)
{
    const int b = blockIdx.x >> 3;
    const int htile = blockIdx.x & 7;
    const int tid = threadIdx.x;
    const int wv = tid >> 6;
    const int lane = tid & 63;
    const int kh = wv >> 1;                       // k-half 0/1
    const int hl = ((wv & 1) << 6) | lane;        // 0..127 within tile
    const int h = (htile << 7) | hl;

    float wk[64];
#pragma unroll
    for (int j = 0; j < 64; ++j)
        wk[j] = W1[(size_t)h * NI + (kh << 6) + j];
    const float bias = b1[h];

    __shared__ float red[2][128];

    // wave-uniform x base: koff marked uniform so loads can scalarize
    const int koff = __builtin_amdgcn_readfirstlane(kh << 6);
    const float* __restrict__ xb = x + (size_t)b * NT * NI + koff;

    float v = 0.0f;
    for (int t = 0; t < NT; ++t) {
        const float* __restrict__ xr = xb + (size_t)t * NI;
        float a0 = 0.f, a1 = 0.f, a2 = 0.f, a3 = 0.f;
#pragma unroll
        for (int j = 0; j < 64; j += 4) {
            a0 = fmaf(xr[j + 0], wk[j + 0], a0);
            a1 = fmaf(xr[j + 1], wk[j + 1], a1);
            a2 = fmaf(xr[j + 2], wk[j + 2], a2);
            a3 = fmaf(xr[j + 3], wk[j + 3], a3);
        }
        const float partial = (a0 + a1) + (a2 + a3);
        if (kh) red[t & 1][hl] = partial;
        __syncthreads();
        if (!kh) {
            const float h1 = partial + red[t & 1][hl] + bias;
            v = fmaf(h1 - v, 0.5f, v);   // v += (h1 - v)/tau, tau = 2
            const bool sp = (v >= 1.0f);
            v = sp ? 0.0f : v;
            const unsigned long long m = __ballot(sp);
            if (lane == 0)
                s1bits[((size_t)t * NB + b) * (NH / 64) + (htile << 1) + (wv & 1)] =
                    (uint64_t)m;
        }
        // slot red[t&1] is next overwritten at t+2, after barrier(t+1): safe.
    }
}

// ---------------------------------------------------------------------------
// Phase B: parallel GEMM2 (no recurrence): h2[m][o] = s1[m][:] . W2T[:][o].
// grid = 2048 m-tiles (128 rows each; note m = t*128+b), block = 4 waves,
// wave owns a 32-o tile (o0 wave-uniform). Per lane: 2 m rows (m0, m0+64),
// acc[2][32]. Per k: 2x bfe + 2x cvt + 64 v_fmac with SGPR W2T row.
// No LDS, no barriers. Spike words per-lane via VMEM (1 dword per 32 k).
// ---------------------------------------------------------------------------
__global__ __launch_bounds__(256, 4) void snn_phaseB(
    const uint64_t* __restrict__ s1bits, const float* __restrict__ W2T,
    float* __restrict__ h2)
{
    const int mtile = blockIdx.x;                 // 0..2047
    const int wv = threadIdx.x >> 6;
    const int lane = threadIdx.x & 63;
    const int o0 = __builtin_amdgcn_readfirstlane(wv << 5);  // 0/32/64/96
    const int m0 = (mtile << 7) + lane;           // rows m0 and m0+64

    float acc0[32], acc1[32];
#pragma unroll
    for (int i = 0; i < 32; ++i) { acc0[i] = 0.f; acc1[i] = 0.f; }

    const uint32_t* __restrict__ sp0 =
        (const uint32_t*)(s1bits + (size_t)m0 * (NH / 64));
    const uint32_t* __restrict__ sp1 =
        (const uint32_t*)(s1bits + (size_t)(m0 + 64) * (NH / 64));
    const float* __restrict__ wbase = W2T + o0;

    for (int kw = 0; kw < NH / 32; ++kw) {        // 32 words of 32 k
        const uint32_t w0 = sp0[kw];
        const uint32_t w1 = sp1[kw];
        const float* __restrict__ wr = wbase + (size_t)(kw << 5) * NO;
#pragma unroll
        for (int kj = 0; kj < 32; ++kj) {
            const float f0 = (float)((w0 >> kj) & 1u);
            const float f1 = (float)((w1 >> kj) & 1u);
            const float* __restrict__ wrow = wr + (size_t)kj * NO;
#pragma unroll
            for (int oo = 0; oo < 32; ++oo) {
                const float w = wrow[oo];
                acc0[oo] = fmaf(f0, w, acc0[oo]);
                acc1[oo] = fmaf(f1, w, acc1[oo]);
            }
        }
    }

    float* __restrict__ p0 = h2 + (size_t)m0 * NO + o0;
    float* __restrict__ p1 = h2 + (size_t)(m0 + 64) * NO + o0;
#pragma unroll
    for (int oo = 0; oo < 32; ++oo) p0[oo] = acc0[oo];
#pragma unroll
    for (int oo = 0; oo < 32; ++oo) p1[oo] = acc1[oo];
}

// ---------------------------------------------------------------------------
// Phase D: LIF2 scan + decision-window count. 8192 threads, each runs two
// independent (b,o) scans (ILP-2 to cover load latency). h2 is [t][b][o].
// ---------------------------------------------------------------------------
__global__ __launch_bounds__(256) void snn_phaseD(
    const float* __restrict__ h2, const float* __restrict__ b2,
    float* __restrict__ out)
{
    const int idx = blockIdx.x * 256 + threadIdx.x;  // 0..8191
    const int b = idx >> 7;                          // 0..63
    const int o = idx & 127;
    const float bias = b2[o];

    const float* __restrict__ pa = h2 + (size_t)b * NO + o;
    const float* __restrict__ pb = h2 + (size_t)(b + 64) * NO + o;
    float va = 0.f, vb = 0.f, ca = 0.f, cb = 0.f;
#pragma unroll 8
    for (int t = 0; t < NT; ++t) {
        const float ha = pa[(size_t)t * NB * NO] + bias;
        const float hb = pb[(size_t)t * NB * NO] + bias;
        va = fmaf(ha - va, 0.5f, va);
        vb = fmaf(hb - vb, 0.5f, vb);
        const bool sa = (va >= 1.0f);
        const bool sb = (vb >= 1.0f);
        va = sa ? 0.f : va;
        vb = sb ? 0.f : vb;
        if (t >= NT / 2) {
            ca += sa ? 1.f : 0.f;
            cb += sb ? 1.f : 0.f;
        }
    }
    out[(size_t)b * NO + o] = ca;
    out[(size_t)(b + 64) * NO + o] = cb;
}

extern "C" void kernel_launch(void* const* d_in, const int* in_sizes, int n_in,
                              void* d_out, int out_size, void* d_ws,
                              size_t ws_size, hipStream_t stream)
{
    const float* x  = (const float*)d_in[0];
    const float* W1 = (const float*)d_in[1];
    const float* b1 = (const float*)d_in[2];
    const float* W2 = (const float*)d_in[3];
    const float* b2 = (const float*)d_in[4];
    float* out = (float*)d_out;

    // ws layout: [s1bits 33.55 MB][W2T 0.52 MB][h2 134.2 MB] = 168.3 MB total
    uint8_t* ws = (uint8_t*)d_ws;
    uint64_t* s1bits = (uint64_t*)ws;                       // NT*NB*16 u64
    float* W2T = (float*)(ws + (size_t)NT * NB * (NH / 64) * 8);
    float* h2 = (float*)(ws + (size_t)NT * NB * (NH / 64) * 8 +
                         (size_t)NH * NO * 4);

    w2t_kernel<<<dim3((NH * NO) / 256), dim3(256), 0, stream>>>(W2, W2T);
    snn_phaseA<<<dim3(NB * 8), dim3(256), 0, stream>>>(x, W1, b1, s1bits);
    snn_phaseB<<<dim3((NT * NB) / 128), dim3(256), 0, stream>>>(s1bits, W2T, h2);
    snn_phaseD<<<dim3((NB / 2 * NO) / 256), dim3(256), 0, stream>>>(h2, b2, out);
}